// Round 6
// baseline (481.097 us; speedup 1.0000x reference)
//
#include <hip/hip_runtime.h>

#define BATCH 4
#define SEQ 2048
#define HEADS 16
#define DHEAD 64
#define HID 1024
#define MROWS (BATCH * SEQ)   // 8192
#define QSCALE 0.1803368801111092f   // 0.125 * log2(e): exp2 domain

typedef unsigned short u16;
typedef unsigned int u32;
typedef __attribute__((ext_vector_type(4))) float f32x4;
typedef __attribute__((ext_vector_type(8))) short bf16x8;
typedef __attribute__((ext_vector_type(2))) unsigned int u32x2;
typedef __attribute__((ext_vector_type(4))) unsigned int u32x4;

#define MFMA16(a, b, c) __builtin_amdgcn_mfma_f32_16x16x32_bf16((a), (b), (c), 0, 0, 0)
#define EXP2F(x) __builtin_amdgcn_exp2f(x)

// f32 -> bf16 round-to-nearest-even (finite inputs)
__device__ __forceinline__ u16 f2bf(float f) {
  union { float f; u32 i; } x; x.f = f;
  u32 r = x.i + 0x7fffu + ((x.i >> 16) & 1u);
  return (u16)(r >> 16);
}

// packed f32 pair -> bf16 pair (RNE), one VALU op (T12 primitive).
__device__ __forceinline__ u32 cvtpk(float a, float b) {
  u32 d;
  asm("v_cvt_pk_bf16_f32 %0, %1, %2" : "=v"(d) : "v"(a), "v"(b));
  return d;
}

// async global->LDS, 16 B/lane.  LDS dest must be wave-uniform base + lane*16.
__device__ __forceinline__ void lds16(const u16* g, u16* s) {
  __builtin_amdgcn_global_load_lds(
      (const __attribute__((address_space(1))) void*)g,
      (__attribute__((address_space(3))) void*)s, 16, 0, 0);
}

// VALU staging: 8 fp32 -> 8 bf16 (fallback paths + cvt kernel)
__device__ __forceinline__ void stage8f(const float* __restrict__ g, u16* s) {
  const float4 a = *(const float4*)g;
  const float4 b = *(const float4*)(g + 4);
  ushort4 lo, hi;
  lo.x = f2bf(a.x); lo.y = f2bf(a.y); lo.z = f2bf(a.z); lo.w = f2bf(a.w);
  hi.x = f2bf(b.x); hi.y = f2bf(b.y); hi.z = f2bf(b.z); hi.w = f2bf(b.w);
  *(ushort4*)s = lo;
  *(ushort4*)(s + 4) = hi;
}

// fp32 -> bf16 for up to 7 tensors in one launch.
struct CvtArgs {
  const float* src[7];
  u16* dst[7];
};
__global__ __launch_bounds__(256) void cvt7(CvtArgs args, int yoff, int nact) {
  const int y = blockIdx.y + yoff;
  const int i = (blockIdx.x * 256 + threadIdx.x) * 8;
  if (y < 3) {
    if (i < nact) stage8f(args.src[y] + i, args.dst[y] + i);
  } else {
    if (i < 4 * (1 << 20)) {
      const int j = i >> 20, off = i & ((1 << 20) - 1);
      stage8f(args.src[3 + j] + off, args.dst[3 + j] + off);
    }
  }
}

// ---------------------------------------------------------------------------
// OLD 128x128x(BK=32) core -- kept for the MID/LOW fallback paths only.
// ---------------------------------------------------------------------------
template<bool ADMA, bool BDMA>
__device__ __forceinline__ void gemm_core(
    const void* __restrict__ Av, const void* __restrict__ Wv,
    int tid, int m0, int n0, u16* As, u16* Bs, f32x4 (&acc)[4][4])
{
  const int srow = tid >> 2, cslot = tid & 3;
  const int gc = cslot ^ ((srow >> 1) & 3);   // swizzled global chunk
  const int w = tid >> 6, l = tid & 63;
  const int quad = l >> 4, l15 = l & 15;
  const int sw = (l15 >> 1) & 3;
  const int wm = (w & 1) << 6, wn = (w >> 1) << 6;

  for (int k0 = 0; k0 < HID; k0 += 32) {
    if (ADMA) {
      const u16* ag = (const u16*)Av + (size_t)(m0 + srow) * HID + k0 + gc * 8;
      lds16(ag, &As[tid * 8]);
      lds16(ag + (size_t)64 * HID, &As[2048 + tid * 8]);
    } else {
      const float* ag = (const float*)Av + (size_t)(m0 + srow) * HID + k0 + gc * 8;
      stage8f(ag, &As[srow * 32 + cslot * 8]);
      stage8f(ag + (size_t)64 * HID, &As[(64 + srow) * 32 + cslot * 8]);
    }
    if (BDMA) {
      const u16* bg = (const u16*)Wv + (size_t)(n0 + srow) * HID + k0 + gc * 8;
      lds16(bg, &Bs[tid * 8]);
      lds16(bg + (size_t)64 * HID, &Bs[2048 + tid * 8]);
    } else {
      const float* bg = (const float*)Wv + (size_t)(n0 + srow) * HID + k0 + gc * 8;
      stage8f(bg, &Bs[srow * 32 + cslot * 8]);
      stage8f(bg + (size_t)64 * HID, &Bs[(64 + srow) * 32 + cslot * 8]);
    }
    __syncthreads();

    bf16x8 a[4], b[4];
    #pragma unroll
    for (int i = 0; i < 4; ++i)
      a[i] = *(const bf16x8*)&As[(wm + i * 16 + l15) * 32 + (quad ^ sw) * 8];
    #pragma unroll
    for (int j = 0; j < 4; ++j)
      b[j] = *(const bf16x8*)&Bs[(wn + j * 16 + l15) * 32 + (quad ^ sw) * 8];
    #pragma unroll
    for (int i = 0; i < 4; ++i)
      #pragma unroll
      for (int j = 0; j < 4; ++j)
        acc[i][j] = MFMA16(a[i], b[j], acc[i][j]);
    __syncthreads();
  }
}

// Fallback fused QKV (MID/LOW).  Epilogue semantics documented at gemm_qkv2.
template<bool ADMA, bool BDMA>
__global__ __launch_bounds__(256) void gemm_qkv(
    const void* __restrict__ xq, const void* __restrict__ xk,
    const void* __restrict__ xv,
    const void* __restrict__ wqv, const void* __restrict__ wkv,
    const void* __restrict__ wvv,
    const float* __restrict__ bq, const float* __restrict__ bk,
    const float* __restrict__ bv, const int* __restrict__ Mask,
    u16* __restrict__ qh, u16* __restrict__ kh, u16* __restrict__ vt)
{
  __shared__ u16 As[128 * 32];
  __shared__ u16 Bs[128 * 32];
  const int z = blockIdx.z;
  const void* A = (z == 0) ? xq : (z == 1) ? xk : xv;
  const void* W = (z == 0) ? wqv : (z == 1) ? wkv : wvv;
  const float* Bias = (z == 0) ? bq : (z == 1) ? bk : bv;

  const int tid = threadIdx.x;
  const int m0 = blockIdx.x << 7, n0 = blockIdx.y << 7;
  f32x4 acc[4][4] = {};
  gemm_core<ADMA, BDMA>(A, W, tid, m0, n0, As, Bs, acc);

  const int w = tid >> 6, l = tid & 63;
  const int quad = l >> 4, l15 = l & 15;
  const int wm = (w & 1) << 6, wn = (w >> 1) << 6;

  if (z <= 1) {
    u16* Out = (z == 0) ? qh : kh;
    #pragma unroll
    for (int i = 0; i < 4; ++i) {
      float fl[4];
      #pragma unroll
      for (int r = 0; r < 4; ++r) {
        const int m = m0 + wm + i * 16 + (quad << 2) + r;
        fl[r] = (z == 0) ? (Mask[m] ? QSCALE : 0.f) : 1.f;
      }
      #pragma unroll
      for (int j = 0; j < 4; ++j) {
        const int n = n0 + wn + j * 16 + l15;
        const float bias = Bias[n];
        const int h = n >> 6, d = n & 63;
        #pragma unroll
        for (int r = 0; r < 4; ++r) {
          const int m = m0 + wm + i * 16 + (quad << 2) + r;
          const int bb = m >> 11, s = m & (SEQ - 1);
          Out[((size_t)(bb * HEADS + h) * SEQ + s) * DHEAD + d] =
              f2bf((acc[i][j][r] + bias) * fl[r]);
        }
      }
    }
  } else {
    const int sblk = (m0 + wm) & (SEQ - 1);
    const int bb = (m0 + wm) >> 11;
    #pragma unroll
    for (int j = 0; j < 4; ++j) {
      const int n = n0 + wn + j * 16 + l15;
      const float bias = Bias[n];
      const int h = n >> 6, d = n & 63;
      u16* base = vt + ((size_t)(bb * HEADS + h) * DHEAD + d) * SEQ + sblk;
      #pragma unroll
      for (int r = 0; r < 4; ++r) {
        u32x2 pk;
        pk.x = cvtpk(acc[0][j][r] + bias, acc[1][j][r] + bias);
        pk.y = cvtpk(acc[2][j][r] + bias, acc[3][j][r] + bias);
        *(u32x2*)(base + ((quad << 2) + r) * 4) = pk;
      }
    }
  }
}

// Fallback output projection (MID/LOW)
template<bool BDMA>
__global__ __launch_bounds__(256) void gemm_out(
    const u16* __restrict__ hidden, const void* __restrict__ wov,
    const float* __restrict__ bo, float* __restrict__ Out)
{
  __shared__ u16 As[128 * 32];
  __shared__ u16 Bs[128 * 32];
  const int tid = threadIdx.x;
  const int m0 = blockIdx.x << 7, n0 = blockIdx.y << 7;
  f32x4 acc[4][4] = {};
  gemm_core<true, BDMA>(hidden, wov, tid, m0, n0, As, Bs, acc);

  const int w = tid >> 6, l = tid & 63;
  const int quad = l >> 4, l15 = l & 15;
  const int wm = (w & 1) << 6, wn = (w >> 1) << 6;
  #pragma unroll
  for (int j = 0; j < 4; ++j) {
    const int n = n0 + wn + j * 16 + l15;
    const float bias = bo[n];
    #pragma unroll
    for (int i = 0; i < 4; ++i) {
      const int mb = m0 + wm + i * 16 + (quad << 2);
      #pragma unroll
      for (int r = 0; r < 4; ++r)
        Out[(size_t)(mb + r) * HID + n] = acc[i][j][r] + bias;
    }
  }
}

// ---------------------------------------------------------------------------
// Pipelined 256x128x(BK=64) core (FULL path).  512 thr = 8 waves (4M x 2N),
// wave tile 64x64 (acc 4x4 f32x4).  TRIPLE-buffered LDS (144 KB), 2-deep
// counted-vmcnt prefetch (T3/T4).  Unchanged from R5 (neutral vs R4; kept --
// structural 8-phase rewrite is a future round).
// ---------------------------------------------------------------------------
__device__ __forceinline__ void core256(
    const u16* __restrict__ A, const u16* __restrict__ W,
    int tid, int m0, int n0, u16* As2, u16* Bs2, f32x4 (&acc)[4][4])
{
  const int l = tid & 63;
  const int quad = l >> 4, l15 = l & 15;
  const int sw7 = l15 & 7;
  const int w = tid >> 6;
  const int wm = (w & 3) << 6, wn = (w >> 2) << 6;
  const int srow = tid >> 3, sslot = tid & 7;   // staging: row-in-part, slot
  const int sgc = sslot ^ (srow & 7);           // content chunk (global side)

  const u16* aB = A + (size_t)(m0 + srow) * HID + sgc * 8;
  const u16* bB = W + (size_t)(n0 + srow) * HID + sgc * 8;

  // prologue: tiles 0,1 -> buffers 0,1 (order: per-tile A then B, 6 loads/tile)
  #pragma unroll
  for (int tt = 0; tt < 2; ++tt) {
    #pragma unroll
    for (int p = 0; p < 4; ++p)
      lds16(aB + (size_t)p * 64 * HID + tt * 64,
            As2 + tt * 16384 + p * 4096 + tid * 8);
    #pragma unroll
    for (int p = 0; p < 2; ++p)
      lds16(bB + (size_t)p * 64 * HID + tt * 64,
            Bs2 + tt * 8192 + p * 4096 + tid * 8);
  }

  #pragma unroll
  for (int t = 0; t < HID / 64; ++t) {
    if (t < HID / 64 - 1)
      asm volatile("s_waitcnt vmcnt(6)" ::: "memory");  // tile t landed
    else
      asm volatile("s_waitcnt vmcnt(0)" ::: "memory");  // last tile
    __builtin_amdgcn_s_barrier();                       // publish tile t
    __builtin_amdgcn_sched_barrier(0);

    if (t < HID / 64 - 2) {   // stage tile t+2 into the 3rd buffer
      const int kk = (t + 2) << 6;
      u16* ad = As2 + ((t + 2) % 3) * 16384;
      u16* bd = Bs2 + ((t + 2) % 3) * 8192;
      #pragma unroll
      for (int p = 0; p < 4; ++p)
        lds16(aB + (size_t)p * 64 * HID + kk, ad + p * 4096 + tid * 8);
      #pragma unroll
      for (int p = 0; p < 2; ++p)
        lds16(bB + (size_t)p * 64 * HID + kk, bd + p * 4096 + tid * 8);
    }

    const u16* Ab = As2 + (t % 3) * 16384;
    const u16* Bb = Bs2 + (t % 3) * 8192;
    #pragma unroll
    for (int ks = 0; ks < 2; ++ks) {
      const int cc = ((ks << 2) | quad) ^ sw7;
      bf16x8 a[4], b[4];
      #pragma unroll
      for (int i = 0; i < 4; ++i)
        a[i] = *(const bf16x8*)&Ab[(wm + i * 16 + l15) * 64 + cc * 8];
      #pragma unroll
      for (int j = 0; j < 4; ++j)
        b[j] = *(const bf16x8*)&Bb[(wn + j * 16 + l15) * 64 + cc * 8];
      __builtin_amdgcn_s_setprio(1);
      #pragma unroll
      for (int i = 0; i < 4; ++i)
        #pragma unroll
        for (int j = 0; j < 4; ++j)
          acc[i][j] = MFMA16(a[i], b[j], acc[i][j]);
      __builtin_amdgcn_s_setprio(0);
    }
  }
  asm volatile("s_waitcnt vmcnt(0)" ::: "memory");  // drain before LDS death
}

// Fused QKV projection, pipelined core.  768 blocks = 3 exact rounds at
// 1 block/CU.  XCD-chunked bijective remap: nid = (lin&7)*96 + lin>>3.
// Epilogues: z=0 mask*QSCALE; z=2 V^T key-perm (see attn_mfma notes).
__global__ __launch_bounds__(512, 1) void gemm_qkv2(
    const u16* __restrict__ xq, const u16* __restrict__ xk,
    const u16* __restrict__ xv,
    const u16* __restrict__ wqv, const u16* __restrict__ wkv,
    const u16* __restrict__ wvv,
    const float* __restrict__ bq, const float* __restrict__ bk,
    const float* __restrict__ bv, const int* __restrict__ Mask,
    u16* __restrict__ qh, u16* __restrict__ kh, u16* __restrict__ vt)
{
  __shared__ u16 As2[3 * 16384];  // 96 KB
  __shared__ u16 Bs2[3 * 8192];   // 48 KB
  const int tid = threadIdx.x;

  const int lin = blockIdx.x;
  const int nid = (lin & 7) * 96 + (lin >> 3);
  const int z = nid >> 8;
  const int rem = nid & 255;
  const int m0 = (rem >> 3) << 8, n0 = (rem & 7) << 7;

  const u16* A = (z == 0) ? xq : (z == 1) ? xk : xv;
  const u16* W = (z == 0) ? wqv : (z == 1) ? wkv : wvv;
  const float* Bias = (z == 0) ? bq : (z == 1) ? bk : bv;

  f32x4 acc[4][4] = {};
  core256(A, W, tid, m0, n0, As2, Bs2, acc);

  const int w = tid >> 6, l = tid & 63;
  const int quad = l >> 4, l15 = l & 15;
  const int wm = (w & 3) << 6, wn = (w >> 2) << 6;

  if (z <= 1) {
    u16* Out = (z == 0) ? qh : kh;
    #pragma unroll
    for (int i = 0; i < 4; ++i) {
      float fl[4];
      #pragma unroll
      for (int r = 0; r < 4; ++r) {
        const int m = m0 + wm + i * 16 + (quad << 2) + r;
        fl[r] = (z == 0) ? (Mask[m] ? QSCALE : 0.f) : 1.f;
      }
      #pragma unroll
      for (int j = 0; j < 4; ++j) {
        const int n = n0 + wn + j * 16 + l15;
        const float bias = Bias[n];
        const int h = n >> 6, d = n & 63;
        #pragma unroll
        for (int r = 0; r < 4; ++r) {
          const int m = m0 + wm + i * 16 + (quad << 2) + r;
          const int bb = m >> 11, s = m & (SEQ - 1);
          Out[((size_t)(bb * HEADS + h) * SEQ + s) * DHEAD + d] =
              f2bf((acc[i][j][r] + bias) * fl[r]);
        }
      }
    }
  } else {
    const int sblk = (m0 + wm) & (SEQ - 1);
    const int bb = (m0 + wm) >> 11;
    #pragma unroll
    for (int j = 0; j < 4; ++j) {
      const int n = n0 + wn + j * 16 + l15;
      const float bias = Bias[n];
      const int h = n >> 6, d = n & 63;
      u16* base = vt + ((size_t)(bb * HEADS + h) * DHEAD + d) * SEQ + sblk;
      #pragma unroll
      for (int r = 0; r < 4; ++r) {
        u32x2 pk;
        pk.x = cvtpk(acc[0][j][r] + bias, acc[1][j][r] + bias);
        pk.y = cvtpk(acc[2][j][r] + bias, acc[3][j][r] + bias);
        *(u32x2*)(base + ((quad << 2) + r) * 4) = pk;
      }
    }
  }
}

// Output projection, pipelined core.  256 blocks = 1 exact round.
__global__ __launch_bounds__(512, 1) void gemm_out2(
    const u16* __restrict__ hidden, const u16* __restrict__ wov,
    const float* __restrict__ bo, float* __restrict__ Out)
{
  __shared__ u16 As2[3 * 16384];
  __shared__ u16 Bs2[3 * 8192];
  const int tid = threadIdx.x;

  const int lin = blockIdx.x;
  const int nid = (lin & 7) * 32 + (lin >> 3);
  const int m0 = (nid >> 3) << 8, n0 = (nid & 7) << 7;

  f32x4 acc[4][4] = {};
  core256(hidden, wov, tid, m0, n0, As2, Bs2, acc);

  const int w = tid >> 6, l = tid & 63;
  const int quad = l >> 4, l15 = l & 15;
  const int wm = (w & 3) << 6, wn = (w >> 2) << 6;
  #pragma unroll
  for (int j = 0; j < 4; ++j) {
    const int n = n0 + wn + j * 16 + l15;
    const float bias = bo[n];
    #pragma unroll
    for (int i = 0; i < 4; ++i) {
      const int mb = m0 + wm + i * 16 + (quad << 2);
      #pragma unroll
      for (int r = 0; r < 4; ++r)
        Out[(size_t)(mb + r) * HID + n] = acc[i][j][r] + bias;
    }
  }
}

// Flash attention, no-max softmax, SWAPPED-OPERAND form (zero P LDS traffic).
// S^T = mfma(K,Q); P^T packed in-register feeds O^T = mfma(V^T, P^T);
// denominator via mfma(ones, P^T).  Counted-vmcnt pipeline, raw barriers.
//
// R6 change: Q fragments load DIRECTLY from global to registers -- the old
// LDS roundtrip's store-swizzle ^ read-swizzle cancels to identity (content
// chunk = quad), so aq[hh][j] elem e = Q[q0+w*64+j*16+l15][hh*32+quad*8+e]
// is a plain per-lane dwordx4.  Qs LDS deleted: 40 KB -> 24 KB ->
// 6 blocks/CU (12 waves, 3/SIMD) -- 50% more independent waves to hide the
// per-block barrier/vmcnt stalls (occupancy was the R5 limiter at 17.7%).
// Q loads retire via explicit vmcnt(0) BEFORE any lds16, so the loop's
// counted DMA waits (4/8) are unchanged and the compiler's auto-wait for
// the Q registers is already satisfied (no vmcnt(0) inside the loop).
__global__ __launch_bounds__(128, 3) void attn_mfma(
    const u16* __restrict__ QH, const u16* __restrict__ KH,
    const u16* __restrict__ VT, u16* __restrict__ Hidden)
{
  __shared__ u16 Ks[2][2048];      // 8 KB, single-buffered (restage post-QK)
  __shared__ u16 Vt[2][4096];      // 16 KB: [buf][64 d][64 key-slots], swizzled

  const int tid = threadIdx.x;     // 0..127
  const int w = tid >> 6, l = tid & 63;
  const int quad = l >> 4, l15 = l & 15;
  const int sw = (l15 >> 1) & 3;
  const int srow = tid >> 2, cslot = tid & 3;
  const int gc = cslot ^ ((srow >> 1) & 3);   // K staging swizzle
  const int vd = tid >> 3;                    // V staging: row within part
  const int vc = (tid & 7) ^ (vd & 7);        // V staging: content chunk

  const int lin = blockIdx.y * 16 + blockIdx.x;
  const int bh = lin & 63, b = bh >> 4, h = bh & 15;
  const int q0 = (lin >> 6) << 7;

  const u16* qbase = QH + (size_t)bh * SEQ * DHEAD;
  const u16* kbase = KH + (size_t)bh * SEQ * DHEAD;
  const u16* vbase = VT + (size_t)bh * DHEAD * SEQ;

  // Q fragments: direct per-lane global loads (loop-invariant, 32 VGPRs).
  bf16x8 aq[2][4];
  #pragma unroll
  for (int hh = 0; hh < 2; ++hh)
    #pragma unroll
    for (int j = 0; j < 4; ++j)
      aq[hh][j] = *(const bf16x8*)(qbase +
          (size_t)(q0 + w * 64 + j * 16 + l15) * DHEAD + hh * 32 + quad * 8);
  // retire Q before any LDS-DMA: loop vmcnt counts then see only DMAs
  asm volatile("s_waitcnt vmcnt(0)" ::: "memory");

  // K(0) then V(0) DMA -- issue order is what the counted waits rely on
  #pragma unroll
  for (int hh = 0; hh < 2; ++hh)
    #pragma unroll
    for (int part = 0; part < 2; ++part)
      lds16(kbase + (size_t)(part * 32 + srow) * DHEAD + hh * 32 + gc * 8,
            &Ks[hh][part * 1024 + tid * 8]);
  #pragma unroll
  for (int part = 0; part < 4; ++part)
    lds16(vbase + (size_t)(part * 16 + vd) * SEQ + vc * 8,
          &Vt[0][part * 1024 + tid * 8]);

  const bf16x8 ones8 = {0x3F80, 0x3F80, 0x3F80, 0x3F80,
                        0x3F80, 0x3F80, 0x3F80, 0x3F80};  // bf16 1.0 x8
  f32x4 o[4][4] = {};      // O^T accum: [d-tile][q-tile]
  f32x4 lacc[4] = {};      // denominator accum per q-tile
  int cur = 0;

  for (int it = 0; it < SEQ / 64; ++it) {
    asm volatile("s_waitcnt vmcnt(4)" ::: "memory");   // K(it) landed
    __builtin_amdgcn_s_barrier();

    // S^T = K Q^T (log2-domain): 32 MFMA, 8 Ks reads
    f32x4 s[4][4] = {};
    __builtin_amdgcn_s_setprio(1);
    #pragma unroll
    for (int i = 0; i < 4; ++i)
      #pragma unroll
      for (int hh = 0; hh < 2; ++hh) {
        const bf16x8 ak = *(const bf16x8*)
            &Ks[hh][(i * 16 + l15) * 32 + (quad ^ sw) * 8];
        #pragma unroll
        for (int j = 0; j < 4; ++j)
          s[i][j] = MFMA16(ak, aq[hh][j], s[i][j]);
      }
    __builtin_amdgcn_s_setprio(0);
    __builtin_amdgcn_s_barrier();   // all waves done reading Ks

    const int tn = ((it + 1) & (SEQ / 64 - 1)) << 6;
    #pragma unroll
    for (int hh = 0; hh < 2; ++hh)
      #pragma unroll
      for (int part = 0; part < 2; ++part)
        lds16(kbase + (size_t)(tn + part * 32 + srow) * DHEAD + hh * 32 + gc * 8,
              &Ks[hh][part * 1024 + tid * 8]);
    #pragma unroll
    for (int part = 0; part < 4; ++part)
      lds16(vbase + (size_t)(part * 16 + vd) * SEQ + tn + vc * 8,
            &Vt[cur ^ 1][part * 1024 + tid * 8]);

    // P^T = exp2(S^T), packed straight into PV B-fragments (register-only)
    bf16x8 bp[2][4];
    #pragma unroll
    for (int j = 0; j < 4; ++j) {
      float p[4][4];
      #pragma unroll
      for (int i = 0; i < 4; ++i)
        #pragma unroll
        for (int r = 0; r < 4; ++r)
          p[i][r] = EXP2F(s[i][j][r]);
      u32x4 t0, t1;
      t0.x = cvtpk(p[0][0], p[1][0]); t0.y = cvtpk(p[2][0], p[3][0]);
      t0.z = cvtpk(p[0][1], p[1][1]); t0.w = cvtpk(p[2][1], p[3][1]);
      t1.x = cvtpk(p[0][2], p[1][2]); t1.y = cvtpk(p[2][2], p[3][2]);
      t1.z = cvtpk(p[0][3], p[1][3]); t1.w = cvtpk(p[2][3], p[3][3]);
      bp[0][j] = __builtin_bit_cast(bf16x8, t0);
      bp[1][j] = __builtin_bit_cast(bf16x8, t1);
      lacc[j] = MFMA16(ones8, bp[0][j], lacc[j]);
      lacc[j] = MFMA16(ones8, bp[1][j], lacc[j]);
    }

    asm volatile("s_waitcnt vmcnt(8)" ::: "memory");   // V(it) landed
    __builtin_amdgcn_s_barrier();

    // O^T += V^T P^T  (32 MFMA, 8 Vt b128 reads, bp from registers)
    __builtin_amdgcn_s_setprio(1);
    #pragma unroll
    for (int hh = 0; hh < 2; ++hh)
      #pragma unroll
      for (int m = 0; m < 4; ++m) {
        const int d = m * 16 + l15;
        const bf16x8 av = *(const bf16x8*)
            &Vt[cur][d * 64 + (((quad * 2 + hh) ^ (d & 7)) << 3)];
        #pragma unroll
        for (int j = 0; j < 4; ++j)
          o[m][j] = MFMA16(av, bp[hh][j], o[m][j]);
      }
    __builtin_amdgcn_s_setprio(0);
    cur ^= 1;
  }
  asm volatile("s_waitcnt vmcnt(0)" ::: "memory");

  float inv[4];
  #pragma unroll
  for (int j = 0; j < 4; ++j)
    inv[j] = 1.f / lacc[j][0];

  #pragma unroll
  for (int m = 0; m < 4; ++m)
    #pragma unroll
    for (int j = 0; j < 4; ++j) {
      u32x2 pk;
      pk.x = cvtpk(o[m][j][0] * inv[j], o[m][j][1] * inv[j]);
      pk.y = cvtpk(o[m][j][2] * inv[j], o[m][j][3] * inv[j]);
      *(u32x2*)&Hidden[(size_t)(b * SEQ + q0 + w * 64 + j * 16 + l15) * HID
                       + h * DHEAD + m * 16 + quad * 4] = pk;
    }
}

extern "C" void kernel_launch(void* const* d_in, const int* in_sizes, int n_in,
                              void* d_out, int out_size, void* d_ws, size_t ws_size,
                              hipStream_t stream) {
  const float* q  = (const float*)d_in[0];
  const float* k  = (const float*)d_in[1];
  const float* v  = (const float*)d_in[2];
  const int* mask = (const int*)d_in[3];
  const float* wq = (const float*)d_in[4];
  const float* bq = (const float*)d_in[5];
  const float* wk = (const float*)d_in[6];
  const float* bk = (const float*)d_in[7];
  const float* wv = (const float*)d_in[8];
  const float* bv = (const float*)d_in[9];
  const float* wo = (const float*)d_in[10];
  const float* bo = (const float*)d_in[11];

  const size_t SEG = (size_t)MROWS * HID;   // 8388608
  const size_t WSEG = (size_t)HID * HID;    // 1048576 = 1<<20
  const dim3 gq(MROWS / 128, HID / 128, 3); // fallback fused QKV
  const dim3 go(MROWS / 128, HID / 128);
  const dim3 ga(SEQ / 128, BATCH * HEADS);  // 16 x 64

  const size_t planFULL = (6 * SEG + 4 * WSEG) * sizeof(u16);  // ~104 MB
  const size_t planMID  = (4 * SEG + 4 * WSEG) * sizeof(u16);  // ~75.5 MB

  if (ws_size >= planFULL) {
    // FULL: everything bf16; pipelined 256x128 GEMMs (triple-buffered).
    u16* qb  = (u16*)d_ws;
    u16* kb  = qb + SEG;
    u16* vb  = kb + SEG;
    u16* qh  = vb + SEG;
    u16* kh  = qh + SEG;
    u16* vt  = kh + SEG;
    u16* wqb = vt + SEG;
    u16* wkb = wqb + WSEG;
    u16* wvb = wkb + WSEG;
    u16* wob = wvb + WSEG;
    u16* hidden = qb;  // alias (qb dead after gemm_qkv2)

    CvtArgs ca;
    ca.src[0] = q;  ca.dst[0] = qb;
    ca.src[1] = k;  ca.dst[1] = kb;
    ca.src[2] = v;  ca.dst[2] = vb;
    ca.src[3] = wq; ca.dst[3] = wqb;
    ca.src[4] = wk; ca.dst[4] = wkb;
    ca.src[5] = wv; ca.dst[5] = wvb;
    ca.src[6] = wo; ca.dst[6] = wob;
    cvt7<<<dim3(SEG / 2048, 4), 256, 0, stream>>>(ca, 0, (int)SEG);

    gemm_qkv2<<<dim3(768), 512, 0, stream>>>(qb, kb, vb, wqb, wkb, wvb,
                                             bq, bk, bv, mask, qh, kh, vt);
    attn_mfma<<<ga, 128, 0, stream>>>(qh, kh, vt, hidden);
    gemm_out2<<<dim3(256), 512, 0, stream>>>(hidden, wob, bo, (float*)d_out);
  } else if (ws_size >= planMID) {
    // MID: weights bf16-DMA, fp32 activations VALU-staged (fallback kernels)
    u16* wqb = (u16*)d_ws;
    u16* wkb = wqb + WSEG;
    u16* wvb = wkb + WSEG;
    u16* wob = wvb + WSEG;
    u16* qh = wob + WSEG;
    u16* kh = qh + SEG;
    u16* vt = kh + SEG;
    u16* hidden = vt + SEG;

    CvtArgs ca;
    ca.src[0] = ca.src[1] = ca.src[2] = q;  // unused slots
    ca.dst[0] = ca.dst[1] = ca.dst[2] = wqb;
    ca.src[3] = wq; ca.dst[3] = wqb;
    ca.src[4] = wk; ca.dst[4] = wkb;
    ca.src[5] = wv; ca.dst[5] = wvb;
    ca.src[6] = wo; ca.dst[6] = wob;
    cvt7<<<dim3(4 * WSEG / 2048, 1), 256, 0, stream>>>(ca, 3, 0);

    gemm_qkv<false, true><<<gq, 256, 0, stream>>>(q, k, v, wqb, wkb, wvb,
                                                  bq, bk, bv, mask, qh, kh, vt);
    attn_mfma<<<ga, 128, 0, stream>>>(qh, kh, vt, hidden);
    gemm_out<true><<<go, 256, 0, stream>>>(hidden, wob, bo, (float*)d_out);
  } else {
    // LOW: 64 MiB ws, all fp32 operands VALU-staged
    u16* qh = (u16*)d_ws;
    u16* kh = qh + SEG;
    u16* vt = kh + SEG;
    u16* hidden = vt + SEG;

    gemm_qkv<false, false><<<gq, 256, 0, stream>>>(q, k, v, wq, wk, wv,
                                                   bq, bk, bv, mask, qh, kh, vt);
    attn_mfma<<<ga, 128, 0, stream>>>(qh, kh, vt, hidden);
    gemm_out<false><<<go, 256, 0, stream>>>(hidden, wo, bo, (float*)d_out);
  }
}

// Round 7
// 325.298 us; speedup vs baseline: 1.4789x; 1.4789x over previous
//
#include <hip/hip_runtime.h>

#define BATCH 4
#define SEQ 2048
#define HEADS 16
#define DHEAD 64
#define HID 1024
#define MROWS (BATCH * SEQ)   // 8192
#define QSCALE 0.1803368801111092f   // 0.125 * log2(e): exp2 domain

typedef unsigned short u16;
typedef unsigned int u32;
typedef __attribute__((ext_vector_type(4))) float f32x4;
typedef __attribute__((ext_vector_type(8))) short bf16x8;
typedef __attribute__((ext_vector_type(2))) unsigned int u32x2;
typedef __attribute__((ext_vector_type(4))) unsigned int u32x4;

#define MFMA16(a, b, c) __builtin_amdgcn_mfma_f32_16x16x32_bf16((a), (b), (c), 0, 0, 0)
#define EXP2F(x) __builtin_amdgcn_exp2f(x)

// f32 -> bf16 round-to-nearest-even (finite inputs)
__device__ __forceinline__ u16 f2bf(float f) {
  union { float f; u32 i; } x; x.f = f;
  u32 r = x.i + 0x7fffu + ((x.i >> 16) & 1u);
  return (u16)(r >> 16);
}

// packed f32 pair -> bf16 pair (RNE), one VALU op (T12 primitive).
__device__ __forceinline__ u32 cvtpk(float a, float b) {
  u32 d;
  asm("v_cvt_pk_bf16_f32 %0, %1, %2" : "=v"(d) : "v"(a), "v"(b));
  return d;
}

// async global->LDS, 16 B/lane.  LDS dest must be wave-uniform base + lane*16.
__device__ __forceinline__ void lds16(const u16* g, u16* s) {
  __builtin_amdgcn_global_load_lds(
      (const __attribute__((address_space(1))) void*)g,
      (__attribute__((address_space(3))) void*)s, 16, 0, 0);
}

// VALU staging: 8 fp32 -> 8 bf16 (fallback paths + cvt kernel)
__device__ __forceinline__ void stage8f(const float* __restrict__ g, u16* s) {
  const float4 a = *(const float4*)g;
  const float4 b = *(const float4*)(g + 4);
  ushort4 lo, hi;
  lo.x = f2bf(a.x); lo.y = f2bf(a.y); lo.z = f2bf(a.z); lo.w = f2bf(a.w);
  hi.x = f2bf(b.x); hi.y = f2bf(b.y); hi.z = f2bf(b.z); hi.w = f2bf(b.w);
  *(ushort4*)s = lo;
  *(ushort4*)(s + 4) = hi;
}

// fp32 -> bf16 for up to 7 tensors in one launch.
struct CvtArgs {
  const float* src[7];
  u16* dst[7];
};
__global__ __launch_bounds__(256) void cvt7(CvtArgs args, int yoff, int nact) {
  const int y = blockIdx.y + yoff;
  const int i = (blockIdx.x * 256 + threadIdx.x) * 8;
  if (y < 3) {
    if (i < nact) stage8f(args.src[y] + i, args.dst[y] + i);
  } else {
    if (i < 4 * (1 << 20)) {
      const int j = i >> 20, off = i & ((1 << 20) - 1);
      stage8f(args.src[3 + j] + off, args.dst[3 + j] + off);
    }
  }
}

// ---------------------------------------------------------------------------
// OLD 128x128x(BK=32) core -- kept for the MID/LOW fallback paths only.
// ---------------------------------------------------------------------------
template<bool ADMA, bool BDMA>
__device__ __forceinline__ void gemm_core(
    const void* __restrict__ Av, const void* __restrict__ Wv,
    int tid, int m0, int n0, u16* As, u16* Bs, f32x4 (&acc)[4][4])
{
  const int srow = tid >> 2, cslot = tid & 3;
  const int gc = cslot ^ ((srow >> 1) & 3);   // swizzled global chunk
  const int w = tid >> 6, l = tid & 63;
  const int quad = l >> 4, l15 = l & 15;
  const int sw = (l15 >> 1) & 3;
  const int wm = (w & 1) << 6, wn = (w >> 1) << 6;

  for (int k0 = 0; k0 < HID; k0 += 32) {
    if (ADMA) {
      const u16* ag = (const u16*)Av + (size_t)(m0 + srow) * HID + k0 + gc * 8;
      lds16(ag, &As[tid * 8]);
      lds16(ag + (size_t)64 * HID, &As[2048 + tid * 8]);
    } else {
      const float* ag = (const float*)Av + (size_t)(m0 + srow) * HID + k0 + gc * 8;
      stage8f(ag, &As[srow * 32 + cslot * 8]);
      stage8f(ag + (size_t)64 * HID, &As[(64 + srow) * 32 + cslot * 8]);
    }
    if (BDMA) {
      const u16* bg = (const u16*)Wv + (size_t)(n0 + srow) * HID + k0 + gc * 8;
      lds16(bg, &Bs[tid * 8]);
      lds16(bg + (size_t)64 * HID, &Bs[2048 + tid * 8]);
    } else {
      const float* bg = (const float*)Wv + (size_t)(n0 + srow) * HID + k0 + gc * 8;
      stage8f(bg, &Bs[srow * 32 + cslot * 8]);
      stage8f(bg + (size_t)64 * HID, &Bs[(64 + srow) * 32 + cslot * 8]);
    }
    __syncthreads();

    bf16x8 a[4], b[4];
    #pragma unroll
    for (int i = 0; i < 4; ++i)
      a[i] = *(const bf16x8*)&As[(wm + i * 16 + l15) * 32 + (quad ^ sw) * 8];
    #pragma unroll
    for (int j = 0; j < 4; ++j)
      b[j] = *(const bf16x8*)&Bs[(wn + j * 16 + l15) * 32 + (quad ^ sw) * 8];
    #pragma unroll
    for (int i = 0; i < 4; ++i)
      #pragma unroll
      for (int j = 0; j < 4; ++j)
        acc[i][j] = MFMA16(a[i], b[j], acc[i][j]);
    __syncthreads();
  }
}

// Fallback fused QKV (MID/LOW).  Epilogue semantics documented at gemm_qkv2.
template<bool ADMA, bool BDMA>
__global__ __launch_bounds__(256) void gemm_qkv(
    const void* __restrict__ xq, const void* __restrict__ xk,
    const void* __restrict__ xv,
    const void* __restrict__ wqv, const void* __restrict__ wkv,
    const void* __restrict__ wvv,
    const float* __restrict__ bq, const float* __restrict__ bk,
    const float* __restrict__ bv, const int* __restrict__ Mask,
    u16* __restrict__ qh, u16* __restrict__ kh, u16* __restrict__ vt)
{
  __shared__ u16 As[128 * 32];
  __shared__ u16 Bs[128 * 32];
  const int z = blockIdx.z;
  const void* A = (z == 0) ? xq : (z == 1) ? xk : xv;
  const void* W = (z == 0) ? wqv : (z == 1) ? wkv : wvv;
  const float* Bias = (z == 0) ? bq : (z == 1) ? bk : bv;

  const int tid = threadIdx.x;
  const int m0 = blockIdx.x << 7, n0 = blockIdx.y << 7;
  f32x4 acc[4][4] = {};
  gemm_core<ADMA, BDMA>(A, W, tid, m0, n0, As, Bs, acc);

  const int w = tid >> 6, l = tid & 63;
  const int quad = l >> 4, l15 = l & 15;
  const int wm = (w & 1) << 6, wn = (w >> 1) << 6;

  if (z <= 1) {
    u16* Out = (z == 0) ? qh : kh;
    #pragma unroll
    for (int i = 0; i < 4; ++i) {
      float fl[4];
      #pragma unroll
      for (int r = 0; r < 4; ++r) {
        const int m = m0 + wm + i * 16 + (quad << 2) + r;
        fl[r] = (z == 0) ? (Mask[m] ? QSCALE : 0.f) : 1.f;
      }
      #pragma unroll
      for (int j = 0; j < 4; ++j) {
        const int n = n0 + wn + j * 16 + l15;
        const float bias = Bias[n];
        const int h = n >> 6, d = n & 63;
        #pragma unroll
        for (int r = 0; r < 4; ++r) {
          const int m = m0 + wm + i * 16 + (quad << 2) + r;
          const int bb = m >> 11, s = m & (SEQ - 1);
          Out[((size_t)(bb * HEADS + h) * SEQ + s) * DHEAD + d] =
              f2bf((acc[i][j][r] + bias) * fl[r]);
        }
      }
    }
  } else {
    const int sblk = (m0 + wm) & (SEQ - 1);
    const int bb = (m0 + wm) >> 11;
    #pragma unroll
    for (int j = 0; j < 4; ++j) {
      const int n = n0 + wn + j * 16 + l15;
      const float bias = Bias[n];
      const int h = n >> 6, d = n & 63;
      u16* base = vt + ((size_t)(bb * HEADS + h) * DHEAD + d) * SEQ + sblk;
      #pragma unroll
      for (int r = 0; r < 4; ++r) {
        u32x2 pk;
        pk.x = cvtpk(acc[0][j][r] + bias, acc[1][j][r] + bias);
        pk.y = cvtpk(acc[2][j][r] + bias, acc[3][j][r] + bias);
        *(u32x2*)(base + ((quad << 2) + r) * 4) = pk;
      }
    }
  }
}

// Fallback output projection (MID/LOW)
template<bool BDMA>
__global__ __launch_bounds__(256) void gemm_out(
    const u16* __restrict__ hidden, const void* __restrict__ wov,
    const float* __restrict__ bo, float* __restrict__ Out)
{
  __shared__ u16 As[128 * 32];
  __shared__ u16 Bs[128 * 32];
  const int tid = threadIdx.x;
  const int m0 = blockIdx.x << 7, n0 = blockIdx.y << 7;
  f32x4 acc[4][4] = {};
  gemm_core<true, BDMA>(hidden, wov, tid, m0, n0, As, Bs, acc);

  const int w = tid >> 6, l = tid & 63;
  const int quad = l >> 4, l15 = l & 15;
  const int wm = (w & 1) << 6, wn = (w >> 1) << 6;
  #pragma unroll
  for (int j = 0; j < 4; ++j) {
    const int n = n0 + wn + j * 16 + l15;
    const float bias = bo[n];
    #pragma unroll
    for (int i = 0; i < 4; ++i) {
      const int mb = m0 + wm + i * 16 + (quad << 2);
      #pragma unroll
      for (int r = 0; r < 4; ++r)
        Out[(size_t)(mb + r) * HID + n] = acc[i][j][r] + bias;
    }
  }
}

// ---------------------------------------------------------------------------
// Pipelined 256x128x(BK=64) core (FULL path).  512 thr = 8 waves (4M x 2N),
// wave tile 64x64 (acc 4x4 f32x4).  TRIPLE-buffered LDS (144 KB), 2-deep
// counted-vmcnt prefetch (T3/T4).  Unchanged (structural 8-phase rewrite is
// a future round).
// ---------------------------------------------------------------------------
__device__ __forceinline__ void core256(
    const u16* __restrict__ A, const u16* __restrict__ W,
    int tid, int m0, int n0, u16* As2, u16* Bs2, f32x4 (&acc)[4][4])
{
  const int l = tid & 63;
  const int quad = l >> 4, l15 = l & 15;
  const int sw7 = l15 & 7;
  const int w = tid >> 6;
  const int wm = (w & 3) << 6, wn = (w >> 2) << 6;
  const int srow = tid >> 3, sslot = tid & 7;   // staging: row-in-part, slot
  const int sgc = sslot ^ (srow & 7);           // content chunk (global side)

  const u16* aB = A + (size_t)(m0 + srow) * HID + sgc * 8;
  const u16* bB = W + (size_t)(n0 + srow) * HID + sgc * 8;

  // prologue: tiles 0,1 -> buffers 0,1 (order: per-tile A then B, 6 loads/tile)
  #pragma unroll
  for (int tt = 0; tt < 2; ++tt) {
    #pragma unroll
    for (int p = 0; p < 4; ++p)
      lds16(aB + (size_t)p * 64 * HID + tt * 64,
            As2 + tt * 16384 + p * 4096 + tid * 8);
    #pragma unroll
    for (int p = 0; p < 2; ++p)
      lds16(bB + (size_t)p * 64 * HID + tt * 64,
            Bs2 + tt * 8192 + p * 4096 + tid * 8);
  }

  #pragma unroll
  for (int t = 0; t < HID / 64; ++t) {
    if (t < HID / 64 - 1)
      asm volatile("s_waitcnt vmcnt(6)" ::: "memory");  // tile t landed
    else
      asm volatile("s_waitcnt vmcnt(0)" ::: "memory");  // last tile
    __builtin_amdgcn_s_barrier();                       // publish tile t
    __builtin_amdgcn_sched_barrier(0);

    if (t < HID / 64 - 2) {   // stage tile t+2 into the 3rd buffer
      const int kk = (t + 2) << 6;
      u16* ad = As2 + ((t + 2) % 3) * 16384;
      u16* bd = Bs2 + ((t + 2) % 3) * 8192;
      #pragma unroll
      for (int p = 0; p < 4; ++p)
        lds16(aB + (size_t)p * 64 * HID + kk, ad + p * 4096 + tid * 8);
      #pragma unroll
      for (int p = 0; p < 2; ++p)
        lds16(bB + (size_t)p * 64 * HID + kk, bd + p * 4096 + tid * 8);
    }

    const u16* Ab = As2 + (t % 3) * 16384;
    const u16* Bb = Bs2 + (t % 3) * 8192;
    #pragma unroll
    for (int ks = 0; ks < 2; ++ks) {
      const int cc = ((ks << 2) | quad) ^ sw7;
      bf16x8 a[4], b[4];
      #pragma unroll
      for (int i = 0; i < 4; ++i)
        a[i] = *(const bf16x8*)&Ab[(wm + i * 16 + l15) * 64 + cc * 8];
      #pragma unroll
      for (int j = 0; j < 4; ++j)
        b[j] = *(const bf16x8*)&Bb[(wn + j * 16 + l15) * 64 + cc * 8];
      __builtin_amdgcn_s_setprio(1);
      #pragma unroll
      for (int i = 0; i < 4; ++i)
        #pragma unroll
        for (int j = 0; j < 4; ++j)
          acc[i][j] = MFMA16(a[i], b[j], acc[i][j]);
      __builtin_amdgcn_s_setprio(0);
    }
  }
  asm volatile("s_waitcnt vmcnt(0)" ::: "memory");  // drain before LDS death
}

// Fused QKV projection, pipelined core.  768 blocks = 3 exact rounds at
// 1 block/CU.  XCD-chunked bijective remap: nid = (lin&7)*96 + lin>>3.
// Epilogues: z=0 mask*QSCALE; z=2 V^T key-perm (see attn_mfma notes).
__global__ __launch_bounds__(512, 1) void gemm_qkv2(
    const u16* __restrict__ xq, const u16* __restrict__ xk,
    const u16* __restrict__ xv,
    const u16* __restrict__ wqv, const u16* __restrict__ wkv,
    const u16* __restrict__ wvv,
    const float* __restrict__ bq, const float* __restrict__ bk,
    const float* __restrict__ bv, const int* __restrict__ Mask,
    u16* __restrict__ qh, u16* __restrict__ kh, u16* __restrict__ vt)
{
  __shared__ u16 As2[3 * 16384];  // 96 KB
  __shared__ u16 Bs2[3 * 8192];   // 48 KB
  const int tid = threadIdx.x;

  const int lin = blockIdx.x;
  const int nid = (lin & 7) * 96 + (lin >> 3);
  const int z = nid >> 8;
  const int rem = nid & 255;
  const int m0 = (rem >> 3) << 8, n0 = (rem & 7) << 7;

  const u16* A = (z == 0) ? xq : (z == 1) ? xk : xv;
  const u16* W = (z == 0) ? wqv : (z == 1) ? wkv : wvv;
  const float* Bias = (z == 0) ? bq : (z == 1) ? bk : bv;

  f32x4 acc[4][4] = {};
  core256(A, W, tid, m0, n0, As2, Bs2, acc);

  const int w = tid >> 6, l = tid & 63;
  const int quad = l >> 4, l15 = l & 15;
  const int wm = (w & 3) << 6, wn = (w >> 2) << 6;

  if (z <= 1) {
    u16* Out = (z == 0) ? qh : kh;
    #pragma unroll
    for (int i = 0; i < 4; ++i) {
      float fl[4];
      #pragma unroll
      for (int r = 0; r < 4; ++r) {
        const int m = m0 + wm + i * 16 + (quad << 2) + r;
        fl[r] = (z == 0) ? (Mask[m] ? QSCALE : 0.f) : 1.f;
      }
      #pragma unroll
      for (int j = 0; j < 4; ++j) {
        const int n = n0 + wn + j * 16 + l15;
        const float bias = Bias[n];
        const int h = n >> 6, d = n & 63;
        #pragma unroll
        for (int r = 0; r < 4; ++r) {
          const int m = m0 + wm + i * 16 + (quad << 2) + r;
          const int bb = m >> 11, s = m & (SEQ - 1);
          Out[((size_t)(bb * HEADS + h) * SEQ + s) * DHEAD + d] =
              f2bf((acc[i][j][r] + bias) * fl[r]);
        }
      }
    }
  } else {
    const int sblk = (m0 + wm) & (SEQ - 1);
    const int bb = (m0 + wm) >> 11;
    #pragma unroll
    for (int j = 0; j < 4; ++j) {
      const int n = n0 + wn + j * 16 + l15;
      const float bias = Bias[n];
      const int h = n >> 6, d = n & 63;
      u16* base = vt + ((size_t)(bb * HEADS + h) * DHEAD + d) * SEQ + sblk;
      #pragma unroll
      for (int r = 0; r < 4; ++r) {
        u32x2 pk;
        pk.x = cvtpk(acc[0][j][r] + bias, acc[1][j][r] + bias);
        pk.y = cvtpk(acc[2][j][r] + bias, acc[3][j][r] + bias);
        *(u32x2*)(base + ((quad << 2) + r) * 4) = pk;
      }
    }
  }
}

// Output projection, pipelined core.  256 blocks = 1 exact round.
__global__ __launch_bounds__(512, 1) void gemm_out2(
    const u16* __restrict__ hidden, const u16* __restrict__ wov,
    const float* __restrict__ bo, float* __restrict__ Out)
{
  __shared__ u16 As2[3 * 16384];
  __shared__ u16 Bs2[3 * 8192];
  const int tid = threadIdx.x;

  const int lin = blockIdx.x;
  const int nid = (lin & 7) * 32 + (lin >> 3);
  const int m0 = (nid >> 3) << 8, n0 = (nid & 7) << 7;

  f32x4 acc[4][4] = {};
  core256(hidden, wov, tid, m0, n0, As2, Bs2, acc);

  const int w = tid >> 6, l = tid & 63;
  const int quad = l >> 4, l15 = l & 15;
  const int wm = (w & 3) << 6, wn = (w >> 2) << 6;
  #pragma unroll
  for (int j = 0; j < 4; ++j) {
    const int n = n0 + wn + j * 16 + l15;
    const float bias = bo[n];
    #pragma unroll
    for (int i = 0; i < 4; ++i) {
      const int mb = m0 + wm + i * 16 + (quad << 2);
      #pragma unroll
      for (int r = 0; r < 4; ++r)
        Out[(size_t)(mb + r) * HID + n] = acc[i][j][r] + bias;
    }
  }
}

// Flash attention, no-max softmax, SWAPPED-OPERAND form (zero P LDS traffic).
// S^T = mfma(K,Q); P^T packed in-register feeds O^T = mfma(V^T, P^T);
// denominator via mfma(ones, P^T).  Counted-vmcnt pipeline, raw barriers.
//
// Q fragments load DIRECTLY from global to registers (LDS roundtrip swizzle
// cancels to identity); Qs LDS deleted: 24 KB total -> up to 6 blocks/CU.
// LAUNCH BOUNDS: (128, 2) -- NOT 3.  R6's (128,3) capped arch-VGPRs at 84
// (512-budget/3, arch/accum split) and spilled ~100 regs to scratch:
// WRITE_SIZE 16->360 MB, 74->237 us.  At (128,2) this register set compiles
// to ~112 VGPR, zero spill, and occupancy is LDS-limited at 6 blocks/CU
// (12 waves = 3/SIMD) -- the occupancy gain without the spill.
__global__ __launch_bounds__(128, 2) void attn_mfma(
    const u16* __restrict__ QH, const u16* __restrict__ KH,
    const u16* __restrict__ VT, u16* __restrict__ Hidden)
{
  __shared__ u16 Ks[2][2048];      // 8 KB, single-buffered (restage post-QK)
  __shared__ u16 Vt[2][4096];      // 16 KB: [buf][64 d][64 key-slots], swizzled

  const int tid = threadIdx.x;     // 0..127
  const int w = tid >> 6, l = tid & 63;
  const int quad = l >> 4, l15 = l & 15;
  const int sw = (l15 >> 1) & 3;
  const int srow = tid >> 2, cslot = tid & 3;
  const int gc = cslot ^ ((srow >> 1) & 3);   // K staging swizzle
  const int vd = tid >> 3;                    // V staging: row within part
  const int vc = (tid & 7) ^ (vd & 7);        // V staging: content chunk

  const int lin = blockIdx.y * 16 + blockIdx.x;
  const int bh = lin & 63, b = bh >> 4, h = bh & 15;
  const int q0 = (lin >> 6) << 7;

  const u16* qbase = QH + (size_t)bh * SEQ * DHEAD;
  const u16* kbase = KH + (size_t)bh * SEQ * DHEAD;
  const u16* vbase = VT + (size_t)bh * DHEAD * SEQ;

  // Q fragments: direct per-lane global loads (loop-invariant, 32 VGPRs).
  bf16x8 aq[2][4];
  #pragma unroll
  for (int hh = 0; hh < 2; ++hh)
    #pragma unroll
    for (int j = 0; j < 4; ++j)
      aq[hh][j] = *(const bf16x8*)(qbase +
          (size_t)(q0 + w * 64 + j * 16 + l15) * DHEAD + hh * 32 + quad * 8);
  // retire Q before any LDS-DMA: loop vmcnt counts then see only DMAs
  asm volatile("s_waitcnt vmcnt(0)" ::: "memory");

  // K(0) then V(0) DMA -- issue order is what the counted waits rely on
  #pragma unroll
  for (int hh = 0; hh < 2; ++hh)
    #pragma unroll
    for (int part = 0; part < 2; ++part)
      lds16(kbase + (size_t)(part * 32 + srow) * DHEAD + hh * 32 + gc * 8,
            &Ks[hh][part * 1024 + tid * 8]);
  #pragma unroll
  for (int part = 0; part < 4; ++part)
    lds16(vbase + (size_t)(part * 16 + vd) * SEQ + vc * 8,
          &Vt[0][part * 1024 + tid * 8]);

  const bf16x8 ones8 = {0x3F80, 0x3F80, 0x3F80, 0x3F80,
                        0x3F80, 0x3F80, 0x3F80, 0x3F80};  // bf16 1.0 x8
  f32x4 o[4][4] = {};      // O^T accum: [d-tile][q-tile]
  f32x4 lacc[4] = {};      // denominator accum per q-tile
  int cur = 0;

  for (int it = 0; it < SEQ / 64; ++it) {
    asm volatile("s_waitcnt vmcnt(4)" ::: "memory");   // K(it) landed
    __builtin_amdgcn_s_barrier();

    // S^T = K Q^T (log2-domain): 32 MFMA, 8 Ks reads
    f32x4 s[4][4] = {};
    __builtin_amdgcn_s_setprio(1);
    #pragma unroll
    for (int i = 0; i < 4; ++i)
      #pragma unroll
      for (int hh = 0; hh < 2; ++hh) {
        const bf16x8 ak = *(const bf16x8*)
            &Ks[hh][(i * 16 + l15) * 32 + (quad ^ sw) * 8];
        #pragma unroll
        for (int j = 0; j < 4; ++j)
          s[i][j] = MFMA16(ak, aq[hh][j], s[i][j]);
      }
    __builtin_amdgcn_s_setprio(0);
    __builtin_amdgcn_s_barrier();   // all waves done reading Ks

    const int tn = ((it + 1) & (SEQ / 64 - 1)) << 6;
    #pragma unroll
    for (int hh = 0; hh < 2; ++hh)
      #pragma unroll
      for (int part = 0; part < 2; ++part)
        lds16(kbase + (size_t)(tn + part * 32 + srow) * DHEAD + hh * 32 + gc * 8,
              &Ks[hh][part * 1024 + tid * 8]);
    #pragma unroll
    for (int part = 0; part < 4; ++part)
      lds16(vbase + (size_t)(part * 16 + vd) * SEQ + tn + vc * 8,
            &Vt[cur ^ 1][part * 1024 + tid * 8]);

    // P^T = exp2(S^T), packed straight into PV B-fragments (register-only)
    bf16x8 bp[2][4];
    #pragma unroll
    for (int j = 0; j < 4; ++j) {
      float p[4][4];
      #pragma unroll
      for (int i = 0; i < 4; ++i)
        #pragma unroll
        for (int r = 0; r < 4; ++r)
          p[i][r] = EXP2F(s[i][j][r]);
      u32x4 t0, t1;
      t0.x = cvtpk(p[0][0], p[1][0]); t0.y = cvtpk(p[2][0], p[3][0]);
      t0.z = cvtpk(p[0][1], p[1][1]); t0.w = cvtpk(p[2][1], p[3][1]);
      t1.x = cvtpk(p[0][2], p[1][2]); t1.y = cvtpk(p[2][2], p[3][2]);
      t1.z = cvtpk(p[0][3], p[1][3]); t1.w = cvtpk(p[2][3], p[3][3]);
      bp[0][j] = __builtin_bit_cast(bf16x8, t0);
      bp[1][j] = __builtin_bit_cast(bf16x8, t1);
      lacc[j] = MFMA16(ones8, bp[0][j], lacc[j]);
      lacc[j] = MFMA16(ones8, bp[1][j], lacc[j]);
    }

    asm volatile("s_waitcnt vmcnt(8)" ::: "memory");   // V(it) landed
    __builtin_amdgcn_s_barrier();

    // O^T += V^T P^T  (32 MFMA, 8 Vt b128 reads, bp from registers)
    __builtin_amdgcn_s_setprio(1);
    #pragma unroll
    for (int hh = 0; hh < 2; ++hh)
      #pragma unroll
      for (int m = 0; m < 4; ++m) {
        const int d = m * 16 + l15;
        const bf16x8 av = *(const bf16x8*)
            &Vt[cur][d * 64 + (((quad * 2 + hh) ^ (d & 7)) << 3)];
        #pragma unroll
        for (int j = 0; j < 4; ++j)
          o[m][j] = MFMA16(av, bp[hh][j], o[m][j]);
      }
    __builtin_amdgcn_s_setprio(0);
    cur ^= 1;
  }
  asm volatile("s_waitcnt vmcnt(0)" ::: "memory");

  float inv[4];
  #pragma unroll
  for (int j = 0; j < 4; ++j)
    inv[j] = 1.f / lacc[j][0];

  #pragma unroll
  for (int m = 0; m < 4; ++m)
    #pragma unroll
    for (int j = 0; j < 4; ++j) {
      u32x2 pk;
      pk.x = cvtpk(o[m][j][0] * inv[j], o[m][j][1] * inv[j]);
      pk.y = cvtpk(o[m][j][2] * inv[j], o[m][j][3] * inv[j]);
      *(u32x2*)&Hidden[(size_t)(b * SEQ + q0 + w * 64 + j * 16 + l15) * HID
                       + h * DHEAD + m * 16 + quad * 4] = pk;
    }
}

extern "C" void kernel_launch(void* const* d_in, const int* in_sizes, int n_in,
                              void* d_out, int out_size, void* d_ws, size_t ws_size,
                              hipStream_t stream) {
  const float* q  = (const float*)d_in[0];
  const float* k  = (const float*)d_in[1];
  const float* v  = (const float*)d_in[2];
  const int* mask = (const int*)d_in[3];
  const float* wq = (const float*)d_in[4];
  const float* bq = (const float*)d_in[5];
  const float* wk = (const float*)d_in[6];
  const float* bk = (const float*)d_in[7];
  const float* wv = (const float*)d_in[8];
  const float* bv = (const float*)d_in[9];
  const float* wo = (const float*)d_in[10];
  const float* bo = (const float*)d_in[11];

  const size_t SEG = (size_t)MROWS * HID;   // 8388608
  const size_t WSEG = (size_t)HID * HID;    // 1048576 = 1<<20
  const dim3 gq(MROWS / 128, HID / 128, 3); // fallback fused QKV
  const dim3 go(MROWS / 128, HID / 128);
  const dim3 ga(SEQ / 128, BATCH * HEADS);  // 16 x 64

  const size_t planFULL = (6 * SEG + 4 * WSEG) * sizeof(u16);  // ~104 MB
  const size_t planMID  = (4 * SEG + 4 * WSEG) * sizeof(u16);  // ~75.5 MB

  if (ws_size >= planFULL) {
    // FULL: everything bf16; pipelined 256x128 GEMMs (triple-buffered).
    u16* qb  = (u16*)d_ws;
    u16* kb  = qb + SEG;
    u16* vb  = kb + SEG;
    u16* qh  = vb + SEG;
    u16* kh  = qh + SEG;
    u16* vt  = kh + SEG;
    u16* wqb = vt + SEG;
    u16* wkb = wqb + WSEG;
    u16* wvb = wkb + WSEG;
    u16* wob = wvb + WSEG;
    u16* hidden = qb;  // alias (qb dead after gemm_qkv2)

    CvtArgs ca;
    ca.src[0] = q;  ca.dst[0] = qb;
    ca.src[1] = k;  ca.dst[1] = kb;
    ca.src[2] = v;  ca.dst[2] = vb;
    ca.src[3] = wq; ca.dst[3] = wqb;
    ca.src[4] = wk; ca.dst[4] = wkb;
    ca.src[5] = wv; ca.dst[5] = wvb;
    ca.src[6] = wo; ca.dst[6] = wob;
    cvt7<<<dim3(SEG / 2048, 4), 256, 0, stream>>>(ca, 0, (int)SEG);

    gemm_qkv2<<<dim3(768), 512, 0, stream>>>(qb, kb, vb, wqb, wkb, wvb,
                                             bq, bk, bv, mask, qh, kh, vt);
    attn_mfma<<<ga, 128, 0, stream>>>(qh, kh, vt, hidden);
    gemm_out2<<<dim3(256), 512, 0, stream>>>(hidden, wob, bo, (float*)d_out);
  } else if (ws_size >= planMID) {
    // MID: weights bf16-DMA, fp32 activations VALU-staged (fallback kernels)
    u16* wqb = (u16*)d_ws;
    u16* wkb = wqb + WSEG;
    u16* wvb = wkb + WSEG;
    u16* wob = wvb + WSEG;
    u16* qh = wob + WSEG;
    u16* kh = qh + SEG;
    u16* vt = kh + SEG;
    u16* hidden = vt + SEG;

    CvtArgs ca;
    ca.src[0] = ca.src[1] = ca.src[2] = q;  // unused slots
    ca.dst[0] = ca.dst[1] = ca.dst[2] = wqb;
    ca.src[3] = wq; ca.dst[3] = wqb;
    ca.src[4] = wk; ca.dst[4] = wkb;
    ca.src[5] = wv; ca.dst[5] = wvb;
    ca.src[6] = wo; ca.dst[6] = wob;
    cvt7<<<dim3(4 * WSEG / 2048, 1), 256, 0, stream>>>(ca, 3, 0);

    gemm_qkv<false, true><<<gq, 256, 0, stream>>>(q, k, v, wqb, wkb, wvb,
                                                  bq, bk, bv, mask, qh, kh, vt);
    attn_mfma<<<ga, 128, 0, stream>>>(qh, kh, vt, hidden);
    gemm_out<true><<<go, 256, 0, stream>>>(hidden, wob, bo, (float*)d_out);
  } else {
    // LOW: 64 MiB ws, all fp32 operands VALU-staged
    u16* qh = (u16*)d_ws;
    u16* kh = qh + SEG;
    u16* vt = kh + SEG;
    u16* hidden = vt + SEG;

    gemm_qkv<false, false><<<gq, 256, 0, stream>>>(q, k, v, wq, wk, wv,
                                                   bq, bk, bv, mask, qh, kh, vt);
    attn_mfma<<<ga, 128, 0, stream>>>(qh, kh, vt, hidden);
    gemm_out<false><<<go, 256, 0, stream>>>(hidden, wo, bo, (float*)d_out);
  }
}